// Round 2
// baseline (313.088 us; speedup 1.0000x reference)
//
#include <hip/hip_runtime.h>
#include <hip/hip_bf16.h>
#include <cstdint>

// LSTM cell: B=8192, I=1024, H=1024.
// R5 = R4 resubmit (R4 bench died to infra, no counters). GEMM is the 256x256
// 8-phase counted-vmcnt schedule (T2+T3+T4+T5):
//   - 8 waves (2M x 4N), BK=64, 128 KiB double-buffered LDS, 1 block/CU
//   - per phase: ds_read subtile || 1 half-tile global_load_lds prefetch ->
//     barrier -> lgkmcnt(0) -> setprio(1) 16xMFMA setprio(0) -> barrier
//   - vmcnt(6) only at phase 4 (once per K-tile): 3 half-tiles stay in
//     flight ACROSS barriers (the m97 structure's vmcnt(0) drain was the
//     ~20% stall; MfmaUtil 43% -> target ~60%)
// Hardening vs R4: hipFuncSetAttribute called unconditionally.
// pack_A / pack_W unchanged from R3.

#define BROWS 8192
#define IH    2048
#define HDIM  1024

typedef __bf16 bf16x4 __attribute__((ext_vector_type(4)));
typedef __bf16 bf16x8 __attribute__((ext_vector_type(8)));
typedef float  f32x4  __attribute__((ext_vector_type(4)));

// ---------------------------------------------------------------- pack_A
__global__ void pack_A(const float* __restrict__ x, const float* __restrict__ hs,
                       __bf16* __restrict__ A) {
    const int tid = threadIdx.x;
    const size_t base = (size_t)blockIdx.x * 2048;   // floats per block
#pragma unroll
    for (int p = 0; p < 2; ++p) {
        size_t e = base + (size_t)p * 1024 + (size_t)tid * 4;
        int row = (int)(e >> 11);
        int col = (int)(e & 2047);
        const float* src = (col < 1024) ? (x + (size_t)row * 1024 + col)
                                        : (hs + (size_t)row * 1024 + (col - 1024));
        float4 v = *(const float4*)src;
        bf16x4 r;
        r[0] = (__bf16)v.x; r[1] = (__bf16)v.y; r[2] = (__bf16)v.z; r[3] = (__bf16)v.w;
        *(bf16x4*)(A + e) = r;
    }
}

// ---------------------------------------------------------------- pack_W
__global__ void pack_W(const float* __restrict__ Wf, const float* __restrict__ Wi,
                       const float* __restrict__ Wc, const float* __restrict__ Wo,
                       __bf16* __restrict__ Wt) {
    __shared__ float tile[32][33];
    int b = blockIdx.x;
    const int g = b & 3; b >>= 2;
    const int nt = b & 31;            // 32 n-tiles
    const int kt = b >> 5;            // 64 k-tiles
    const int n0 = nt * 32, k0 = kt * 32;
    const float* W = (g == 0) ? Wf : (g == 1) ? Wi : (g == 2) ? Wc : Wo;
    const int tid = threadIdx.x;
    {   // phase 1: 256 threads x 1 float4 = 32x32 tile
        const int k = tid >> 3, c = tid & 7;
        *(float4*)&tile[k][c * 4] = *(const float4*)&W[(size_t)(k0 + k) * HDIM + n0 + c * 4];
    }
    __syncthreads();
    {   // phase 2
        const int n = tid >> 3, kq = tid & 7;
        bf16x4 r;
#pragma unroll
        for (int j = 0; j < 4; ++j) r[j] = (__bf16)tile[kq * 4 + j][n];
        *(bf16x4*)&Wt[(size_t)(g * HDIM + n0 + n) * IH + k0 + kq * 4] = r;
    }
}

// ---------------------------------------------------------------- lstm_gemm
// C[8192][4 gates x 1024] = A[8192][2048] x Wt[4096][2048]^T, fused LSTM tail.
// Block tile: 256 rows x (4 gates x 64 h). Waves 2M x 4N; per-wave 128x64.
// Per thread: acc[8 mfrag][4 gate] f32x4; n-frag n == gate (epilogue lane-local).

#define BM  256
#define BK  64
#define NT  (IH / BK)          // 32 K-tiles
#define ATB (BM * BK)          // 16384 elems = 32 KiB per buffer per operand

__device__ __forceinline__ void gload16(const __bf16* g, __bf16* l) {
    __builtin_amdgcn_global_load_lds(
        (const __attribute__((address_space(1))) unsigned*)g,
        (__attribute__((address_space(3))) unsigned*)l, 16, 0, 0);
}

#define LGKM0() do { asm volatile("s_waitcnt lgkmcnt(0)" ::: "memory"); \
                     __builtin_amdgcn_sched_barrier(0); } while (0)
#define VMC6()  asm volatile("s_waitcnt vmcnt(6)" ::: "memory")
#define VMC0()  asm volatile("s_waitcnt vmcnt(0)" ::: "memory")
#define BAR()   __builtin_amdgcn_s_barrier()

// staging: per round, rows rb..rb+63 (c = rb + wave*8 uniform), lane writes
// 16B linearly; global source pre-swizzled by row&7 (== lrow since c%8==0).
#define SA(dst, T, rb) gload16(aA + (size_t)(rb) * IH + (size_t)(T) * BK, \
                               (dst) + ((rb) + wv8) * BK)
#define SB(dst, T, rb) gload16(bB + (size_t)(rb) * 32768 + (size_t)(T) * BK, \
                               (dst) + ((rb) + wv8) * BK)
// half-tiles: Ah0 = rows {0..63,128..191} (mh0 rows of both wr), Ah1 = rest;
//             Bh0 = rows 0..127 (gates 0,1), Bh1 = 128..255 (gates 2,3).
#define ISS_AH0(dst, T) do { SA(dst, T, 0);   SA(dst, T, 128); } while (0)
#define ISS_AH1(dst, T) do { SA(dst, T, 64);  SA(dst, T, 192); } while (0)
#define ISS_BH0(dst, T) do { SB(dst, T, 0);   SB(dst, T, 64);  } while (0)
#define ISS_BH1(dst, T) do { SB(dst, T, 128); SB(dst, T, 192); } while (0)

#define LD_AF(MH, Ac) do { \
    _Pragma("unroll") for (int m_ = 0; m_ < 4; ++m_) \
    _Pragma("unroll") for (int ks_ = 0; ks_ < 2; ++ks_) \
        af[m_][ks_] = *(const bf16x8*)&(Ac)[(wr128 + (MH) * 64 + m_ * 16 + l16) * BK \
                                            + (((ks_ * 4 + quad) ^ sw) << 3)]; \
} while (0)

#define LD_BG(NH, Bc) do { \
    _Pragma("unroll") for (int n_ = 0; n_ < 2; ++n_) \
    _Pragma("unroll") for (int ks_ = 0; ks_ < 2; ++ks_) \
        bg[(NH) * 2 + n_][ks_] = *(const bf16x8*)&(Bc)[(((NH) * 2 + n_) * 64 + wc16 + l16) * BK \
                                                       + (((ks_ * 4 + quad) ^ sw) << 3)]; \
} while (0)

#define MFMA_Q(MH, NH) do { \
    __builtin_amdgcn_s_setprio(1); \
    _Pragma("unroll") for (int n_ = 0; n_ < 2; ++n_) \
    _Pragma("unroll") for (int m_ = 0; m_ < 4; ++m_) \
    _Pragma("unroll") for (int ks_ = 0; ks_ < 2; ++ks_) \
        acc[(MH) * 4 + m_][(NH) * 2 + n_] = __builtin_amdgcn_mfma_f32_16x16x32_bf16( \
            af[m_][ks_], bg[(NH) * 2 + n_][ks_], acc[(MH) * 4 + m_][(NH) * 2 + n_], 0, 0, 0); \
    __builtin_amdgcn_s_setprio(0); \
} while (0)

// One K-tile = 4 phases. Slot-overwrite safety: Ah0(t+2) issued ph2 (readers
// done ph1-bar2), Bh0(t+2) ph3 (read ph1, cached for ph3), Bh1(t+2) ph4 (read
// ph2, cached), Ah1(t+1) ph1 (prev occupant t-1's Ah1 last read ph3 of t-1).
// vmcnt(6) at ph4 retires exactly tile t+1's 4 half-tiles (8 loads).
#define TILE(T, Ac, Bc, An, ISS1, ISS2, VMW) do { \
    LD_AF(0, Ac); LD_BG(0, Bc); \
    if (ISS1) ISS_AH1(An, (T) + 1); \
    BAR(); LGKM0(); \
    MFMA_Q(0, 0); \
    BAR(); \
    LD_BG(1, Bc); \
    if (ISS2) ISS_AH0(Ac, (T) + 2); \
    BAR(); LGKM0(); \
    MFMA_Q(0, 1); \
    BAR(); \
    LD_AF(1, Ac); \
    if (ISS2) ISS_BH0(Bc, (T) + 2); \
    BAR(); LGKM0(); \
    MFMA_Q(1, 0); \
    BAR(); \
    if (ISS2) ISS_BH1(Bc, (T) + 2); \
    BAR(); \
    MFMA_Q(1, 1); \
    if ((VMW) == 6) { VMC6(); } else if ((VMW) == 0) { VMC0(); } \
    BAR(); \
} while (0)

__global__ __launch_bounds__(512, 2) void lstm_gemm(
    const __bf16* __restrict__ A,    // [8192][2048]
    const __bf16* __restrict__ Wt,   // [4096][2048], row g*1024+h
    const float* __restrict__ cell,
    const float* __restrict__ bF_, const float* __restrict__ bI_,
    const float* __restrict__ bC_, const float* __restrict__ bO_,
    float* __restrict__ out)         // [2][8192][1024]
{
    extern __shared__ __bf16 lds[];
    __bf16* Asb = lds;               // [2][ATB]
    __bf16* Bsb = lds + 2 * ATB;     // [2][ATB]

    const int tid  = threadIdx.x;
    const int wave = tid >> 6;       // 0..7
    const int lane = tid & 63;
    const int quad = lane >> 4;
    const int l16  = lane & 15;
    const int sw   = l16 & 7;        // read-side swizzle key (row&7)
    const int wr   = wave >> 2;      // 0..1  (M half)
    const int wc   = wave & 3;       // 0..3  (h quarter of 64)
    const int lrow = lane >> 3;
    const int lk   = ((lane & 7) ^ lrow) << 3;   // pre-swizzled global chunk
    const int wv8  = wave * 8;
    const int wr128 = wr * 128;
    const int wc16  = wc * 16;

    const int m0 = blockIdx.y * BM;
    const int h0 = blockIdx.x * 64;

    const __bf16* aA = A  + (size_t)(m0 + wv8 + lrow) * IH + lk;
    const __bf16* bB = Wt + (size_t)(h0 + wv8 + lrow) * IH + lk;  // +rb*32768 = gate hop

    f32x4 acc[8][4] = {};            // [mfrag][gate]
    bf16x8 af[4][2], bg[4][2];       // [frag][kstep]

    // prologue: tile0 (4 half-tiles) + tile1's first 3; keep 3 in flight
    ISS_AH0(Asb, 0); ISS_BH0(Bsb, 0); ISS_BH1(Bsb, 0); ISS_AH1(Asb, 0);
    ISS_AH0(Asb + ATB, 1); ISS_BH0(Bsb + ATB, 1); ISS_BH1(Bsb + ATB, 1);
    VMC6();
    BAR();

    for (int t = 0; t < NT - 2; ++t) {
        __bf16* Ac = Asb + (t & 1) * ATB;
        __bf16* Bc = Bsb + (t & 1) * ATB;
        __bf16* An = Asb + ((t & 1) ^ 1) * ATB;
        TILE(t, Ac, Bc, An, true, true, 6);
    }
    // NT-2 = 30 (even -> buf0): issue only Ah1(31); full drain for last tile
    TILE(NT - 2, Asb, Bsb, Asb + ATB, true, false, 0);
    // NT-1 = 31 (buf1): pure compute
    TILE(NT - 1, Asb + ATB, Bsb + ATB, Asb, false, false, -1);

    // ---------------- fused LSTM epilogue (lane-local: all 4 gates in-reg)
    const int h = h0 + wc16 + l16;
    const float bFv = bF_[h], bIv = bI_[h], bCv = bC_[h], bOv = bO_[h];
#pragma unroll
    for (int mi = 0; mi < 8; ++mi) {
#pragma unroll
        for (int r = 0; r < 4; ++r) {
            const int m = m0 + wr128 + mi * 16 + quad * 4 + r;
            float pf = acc[mi][0][r] + bFv;
            float pi = acc[mi][1][r] + bIv;
            float pc = acc[mi][2][r] + bCv;
            float po = acc[mi][3][r] + bOv;
            float f  = 1.f / (1.f + __expf(-pf));
            float ig = 1.f / (1.f + __expf(-pi));
            float og = 1.f / (1.f + __expf(-po));
            float e2 = __expf(2.f * pc);
            float cd = (e2 - 1.f) / (e2 + 1.f);          // tanh(pc)
            float cp = cell[(size_t)m * HDIM + h];
            float cn = f * cp + ig * cd;
            float ec = __expf(2.f * cn);
            float tc = (ec - 1.f) / (ec + 1.f);          // tanh(cn)
            out[(size_t)m * HDIM + h] = og * tc;                       // new_hidden
            out[(size_t)BROWS * HDIM + (size_t)m * HDIM + h] = cn;     // new_cell
        }
    }
}

// ---------------------------------------------------------------- launch
extern "C" void kernel_launch(void* const* d_in, const int* in_sizes, int n_in,
                              void* d_out, int out_size, void* d_ws, size_t ws_size,
                              hipStream_t stream) {
    const float* x  = (const float*)d_in[0];
    const float* hs = (const float*)d_in[1];
    const float* cs = (const float*)d_in[2];
    const float* Wf = (const float*)d_in[3];
    const float* bF = (const float*)d_in[4];
    const float* Wi = (const float*)d_in[5];
    const float* bI = (const float*)d_in[6];
    const float* Wc = (const float*)d_in[7];
    const float* bC = (const float*)d_in[8];
    const float* Wo = (const float*)d_in[9];
    const float* bO = (const float*)d_in[10];
    float* out = (float*)d_out;

    __bf16* A  = (__bf16*)d_ws;                                   // 32 MiB
    __bf16* Wt = (__bf16*)((char*)d_ws + (size_t)BROWS * IH * 2); // 16 MiB

    // Unconditional: idempotent, stream-independent (graph-capture legal).
    (void)hipFuncSetAttribute((const void*)lstm_gemm,
                              hipFuncAttributeMaxDynamicSharedMemorySize, 131072);

    pack_A<<<BROWS * IH / 2048, 256, 0, stream>>>(x, hs, A);
    pack_W<<<4 * 32 * 64, 256, 0, stream>>>(Wf, Wi, Wc, Wo, Wt);
    lstm_gemm<<<dim3(HDIM / 64, BROWS / BM), 512, 131072, stream>>>(A, Wt, cs, bF, bI, bC, bO, out);
}

// Round 4
// 311.261 us; speedup vs baseline: 1.0059x; 1.0059x over previous
//
#include <hip/hip_runtime.h>
#include <hip/hip_bf16.h>
#include <cstdint>

// LSTM cell: B=8192, I=1024, H=1024.
// R7: m201-faithful waits on the 8-phase 256x256 schedule.
//  R5 (measured 190us, MfmaUtil 30.6%) matched the verified m201 template
//  EXCEPT its per-phase lgkmcnt(0) also carried sched_barrier(0)+"memory"
//  (m141-class order pin, measured -43% there; 30.6% = ~0.5x the 61%
//  LDS-pipe ceiling of this fragment scheme). R7 uses the template's bare
//  `s_waitcnt lgkmcnt(0)` after each phase barrier -- no sched_barrier, no
//  clobber. Kept from R6: 4-half-tile prefetch distance (vmcnt(8) once per
//  K-tile, every load issued >=4 phases before retirement) and the removal
//  of the redundant phase-4 barrier (its ISS is WAR-gated by the prior
//  barrier; MFMA_Q(1,1) consumes registers only).
//  Pipe budget per phase per CU: 8 waves x 8 ds_read_b128 ~= 256 cyc LDS vs
//  156 cyc MFMA/SIMD -> structural ceiling ~61% MfmaUtil (m201 hits 62%).
// pack_A / pack_W unchanged from R3.

#define BROWS 8192
#define IH    2048
#define HDIM  1024

typedef __bf16 bf16x4 __attribute__((ext_vector_type(4)));
typedef __bf16 bf16x8 __attribute__((ext_vector_type(8)));
typedef float  f32x4  __attribute__((ext_vector_type(4)));

// ---------------------------------------------------------------- pack_A
__global__ void pack_A(const float* __restrict__ x, const float* __restrict__ hs,
                       __bf16* __restrict__ A) {
    const int tid = threadIdx.x;
    const size_t base = (size_t)blockIdx.x * 2048;   // floats per block
#pragma unroll
    for (int p = 0; p < 2; ++p) {
        size_t e = base + (size_t)p * 1024 + (size_t)tid * 4;
        int row = (int)(e >> 11);
        int col = (int)(e & 2047);
        const float* src = (col < 1024) ? (x + (size_t)row * 1024 + col)
                                        : (hs + (size_t)row * 1024 + (col - 1024));
        float4 v = *(const float4*)src;
        bf16x4 r;
        r[0] = (__bf16)v.x; r[1] = (__bf16)v.y; r[2] = (__bf16)v.z; r[3] = (__bf16)v.w;
        *(bf16x4*)(A + e) = r;
    }
}

// ---------------------------------------------------------------- pack_W
__global__ void pack_W(const float* __restrict__ Wf, const float* __restrict__ Wi,
                       const float* __restrict__ Wc, const float* __restrict__ Wo,
                       __bf16* __restrict__ Wt) {
    __shared__ float tile[32][33];
    int b = blockIdx.x;
    const int g = b & 3; b >>= 2;
    const int nt = b & 31;            // 32 n-tiles
    const int kt = b >> 5;            // 64 k-tiles
    const int n0 = nt * 32, k0 = kt * 32;
    const float* W = (g == 0) ? Wf : (g == 1) ? Wi : (g == 2) ? Wc : Wo;
    const int tid = threadIdx.x;
    {   // phase 1: 256 threads x 1 float4 = 32x32 tile
        const int k = tid >> 3, c = tid & 7;
        *(float4*)&tile[k][c * 4] = *(const float4*)&W[(size_t)(k0 + k) * HDIM + n0 + c * 4];
    }
    __syncthreads();
    {   // phase 2
        const int n = tid >> 3, kq = tid & 7;
        bf16x4 r;
#pragma unroll
        for (int j = 0; j < 4; ++j) r[j] = (__bf16)tile[kq * 4 + j][n];
        *(bf16x4*)&Wt[(size_t)(g * HDIM + n0 + n) * IH + k0 + kq * 4] = r;
    }
}

// ---------------------------------------------------------------- lstm_gemm
// C[8192][4 gates x 1024] = A[8192][2048] x Wt[4096][2048]^T, fused LSTM tail.
// Block tile: 256 rows x (4 gates x 64 h). Waves 2M x 4N; per-wave 128x64.

#define BM  256
#define BK  64
#define NT  (IH / BK)          // 32 K-tiles
#define ATB (BM * BK)          // 16384 elems = 32 KiB per buffer per operand

__device__ __forceinline__ void gload16(const __bf16* g, __bf16* l) {
    __builtin_amdgcn_global_load_lds(
        (const __attribute__((address_space(1))) unsigned*)g,
        (__attribute__((address_space(3))) unsigned*)l, 16, 0, 0);
}

#define LGKM()  asm volatile("s_waitcnt lgkmcnt(0)")
#define VMC8()  asm volatile("s_waitcnt vmcnt(8)" ::: "memory")
#define VMC0()  asm volatile("s_waitcnt vmcnt(0)" ::: "memory")
#define BAR()   __builtin_amdgcn_s_barrier()

// staging: per round, rows rb..rb+63 (base = rb + wave*8 uniform), lane writes
// 16B linearly; global source pre-swizzled by row&7 (== lrow since base%8==0).
#define SA(dst, T, rb) gload16(aA + (size_t)(rb) * IH + (size_t)(T) * BK, \
                               (dst) + ((rb) + wv8) * BK)
#define SB(dst, T, rb) gload16(bB + (size_t)(rb) * 32768 + (size_t)(T) * BK, \
                               (dst) + ((rb) + wv8) * BK)
// half-tiles: Ah0 = rows {0..63,128..191} (mfrag 0..3 of both wr), Ah1 = rest;
//             Bh0 = rows 0..127 (gates 0,1), Bh1 = 128..255 (gates 2,3).
#define ISS_AH0(dst, T) do { SA(dst, T, 0);   SA(dst, T, 128); } while (0)
#define ISS_AH1(dst, T) do { SA(dst, T, 64);  SA(dst, T, 192); } while (0)
#define ISS_BH0(dst, T) do { SB(dst, T, 0);   SB(dst, T, 64);  } while (0)
#define ISS_BH1(dst, T) do { SB(dst, T, 128); SB(dst, T, 192); } while (0)

#define LD_AF(MH, Ac) do { \
    _Pragma("unroll") for (int m_ = 0; m_ < 4; ++m_) \
    _Pragma("unroll") for (int ks_ = 0; ks_ < 2; ++ks_) \
        af[m_][ks_] = *(const bf16x8*)&(Ac)[(wr128 + (MH) * 64 + m_ * 16 + l16) * BK \
                                            + (((ks_ * 4 + quad) ^ sw) << 3)]; \
} while (0)

#define LD_BG(NH, Bc) do { \
    _Pragma("unroll") for (int n_ = 0; n_ < 2; ++n_) \
    _Pragma("unroll") for (int ks_ = 0; ks_ < 2; ++ks_) \
        bg[(NH) * 2 + n_][ks_] = *(const bf16x8*)&(Bc)[(((NH) * 2 + n_) * 64 + wc16 + l16) * BK \
                                                       + (((ks_ * 4 + quad) ^ sw) << 3)]; \
} while (0)

#define MFMA_Q(MH, NH) do { \
    __builtin_amdgcn_s_setprio(1); \
    _Pragma("unroll") for (int n_ = 0; n_ < 2; ++n_) \
    _Pragma("unroll") for (int m_ = 0; m_ < 4; ++m_) \
    _Pragma("unroll") for (int ks_ = 0; ks_ < 2; ++ks_) \
        acc[(MH) * 4 + m_][(NH) * 2 + n_] = __builtin_amdgcn_mfma_f32_16x16x32_bf16( \
            af[m_][ks_], bg[(NH) * 2 + n_][ks_], acc[(MH) * 4 + m_][(NH) * 2 + n_], 0, 0, 0); \
    __builtin_amdgcn_s_setprio(0); \
} while (0)

// One K-tile = 4 phases, 7 barriers. WAR safety: each staged overwrite is
// issued only after the barrier that follows its slot's last consumer (the
// consumer MFMA's lgkmcnt waits guarantee the ds_reads completed first).
//   Ah0 read ph1 -> overwritten after bar2; Bh0 read ph1 -> after bar4 (extra
//   margin); Bh1 read ph2 -> after bar6; Ah1 read ph3 -> after bar6.
// RAW safety: VMC8 before the tile-final barrier retires exactly tile t+1's
// 4 half-tiles (8 loads), every one issued >= 4 phases earlier.
#define TILE(T, Ac, Bc, ISS2, VMW) do { \
    LD_AF(0, Ac); LD_BG(0, Bc); \
    BAR(); LGKM(); \
    MFMA_Q(0, 0); \
    BAR(); \
    LD_BG(1, Bc); \
    if (ISS2) ISS_AH0(Ac, (T) + 2); \
    BAR(); LGKM(); \
    MFMA_Q(0, 1); \
    BAR(); \
    LD_AF(1, Ac); \
    if (ISS2) ISS_BH0(Bc, (T) + 2); \
    BAR(); LGKM(); \
    MFMA_Q(1, 0); \
    BAR(); \
    if (ISS2) { ISS_BH1(Bc, (T) + 2); ISS_AH1(Ac, (T) + 2); } \
    MFMA_Q(1, 1); \
    if ((VMW) == 8) { VMC8(); } else if ((VMW) == 0) { VMC0(); } \
    BAR(); \
} while (0)

__global__ __launch_bounds__(512, 2) void lstm_gemm(
    const __bf16* __restrict__ A,    // [8192][2048]
    const __bf16* __restrict__ Wt,   // [4096][2048], row g*1024+h
    const float* __restrict__ cell,
    const float* __restrict__ bF_, const float* __restrict__ bI_,
    const float* __restrict__ bC_, const float* __restrict__ bO_,
    float* __restrict__ out)         // [2][8192][1024]
{
    extern __shared__ __bf16 lds[];
    __bf16* Asb = lds;               // [2][ATB]
    __bf16* Bsb = lds + 2 * ATB;     // [2][ATB]

    const int tid  = threadIdx.x;
    const int wave = tid >> 6;       // 0..7
    const int lane = tid & 63;
    const int quad = lane >> 4;
    const int l16  = lane & 15;
    const int sw   = l16 & 7;        // read-side swizzle key (row&7)
    const int wr   = wave >> 2;      // 0..1  (M half)
    const int wc   = wave & 3;       // 0..3  (h quarter of 64)
    const int lrow = lane >> 3;
    const int lk   = ((lane & 7) ^ lrow) << 3;   // pre-swizzled global chunk
    const int wv8  = wave * 8;
    const int wr128 = wr * 128;
    const int wc16  = wc * 16;

    const int m0 = blockIdx.y * BM;
    const int h0 = blockIdx.x * 64;

    const __bf16* aA = A  + (size_t)(m0 + wv8 + lrow) * IH + lk;
    const __bf16* bB = Wt + (size_t)(h0 + wv8 + lrow) * IH + lk;  // +rb*32768 = gate hop

    f32x4 acc[8][4] = {};            // [mfrag][gate]
    bf16x8 af[4][2], bg[4][2];       // [frag][kstep]

    // prologue: tiles 0 and 1 fully issued (16 loads); vmcnt(8) retires
    // tile 0's 8, leaves tile 1's 8 in flight -- steady-state invariant.
    ISS_AH0(Asb, 0); ISS_BH0(Bsb, 0); ISS_BH1(Bsb, 0); ISS_AH1(Asb, 0);
    ISS_AH0(Asb + ATB, 1); ISS_BH0(Bsb + ATB, 1); ISS_BH1(Bsb + ATB, 1); ISS_AH1(Asb + ATB, 1);
    VMC8();
    BAR();

    for (int t = 0; t < NT - 2; ++t) {
        __bf16* Ac = Asb + (t & 1) * ATB;
        __bf16* Bc = Bsb + (t & 1) * ATB;
        TILE(t, Ac, Bc, true, 8);
    }
    // t = 30 (even -> buf0): no new issues; vmcnt(0) drains tile 31's loads
    TILE(NT - 2, Asb, Bsb, false, 0);
    // t = 31 (buf1): pure compute
    TILE(NT - 1, Asb + ATB, Bsb + ATB, false, -1);

    // ---------------- fused LSTM epilogue (lane-local: all 4 gates in-reg)
    const int h = h0 + wc16 + l16;
    const float bFv = bF_[h], bIv = bI_[h], bCv = bC_[h], bOv = bO_[h];
#pragma unroll
    for (int mi = 0; mi < 8; ++mi) {
#pragma unroll
        for (int r = 0; r < 4; ++r) {
            const int m = m0 + wr128 + mi * 16 + quad * 4 + r;
            float pf = acc[mi][0][r] + bFv;
            float pi = acc[mi][1][r] + bIv;
            float pc = acc[mi][2][r] + bCv;
            float po = acc[mi][3][r] + bOv;
            float f  = 1.f / (1.f + __expf(-pf));
            float ig = 1.f / (1.f + __expf(-pi));
            float og = 1.f / (1.f + __expf(-po));
            float e2 = __expf(2.f * pc);
            float cd = (e2 - 1.f) / (e2 + 1.f);          // tanh(pc)
            float cp = cell[(size_t)m * HDIM + h];
            float cn = f * cp + ig * cd;
            float ec = __expf(2.f * cn);
            float tc = (ec - 1.f) / (ec + 1.f);          // tanh(cn)
            out[(size_t)m * HDIM + h] = og * tc;                       // new_hidden
            out[(size_t)BROWS * HDIM + (size_t)m * HDIM + h] = cn;     // new_cell
        }
    }
}

// ---------------------------------------------------------------- launch
extern "C" void kernel_launch(void* const* d_in, const int* in_sizes, int n_in,
                              void* d_out, int out_size, void* d_ws, size_t ws_size,
                              hipStream_t stream) {
    const float* x  = (const float*)d_in[0];
    const float* hs = (const float*)d_in[1];
    const float* cs = (const float*)d_in[2];
    const float* Wf = (const float*)d_in[3];
    const float* bF = (const float*)d_in[4];
    const float* Wi = (const float*)d_in[5];
    const float* bI = (const float*)d_in[6];
    const float* Wc = (const float*)d_in[7];
    const float* bC = (const float*)d_in[8];
    const float* Wo = (const float*)d_in[9];
    const float* bO = (const float*)d_in[10];
    float* out = (float*)d_out;

    __bf16* A  = (__bf16*)d_ws;                                   // 32 MiB
    __bf16* Wt = (__bf16*)((char*)d_ws + (size_t)BROWS * IH * 2); // 16 MiB

    // Unconditional: idempotent, stream-independent (graph-capture legal).
    (void)hipFuncSetAttribute((const void*)lstm_gemm,
                              hipFuncAttributeMaxDynamicSharedMemorySize, 131072);

    pack_A<<<BROWS * IH / 2048, 256, 0, stream>>>(x, hs, A);
    pack_W<<<4 * 32 * 64, 256, 0, stream>>>(Wf, Wi, Wc, Wo, Wt);
    lstm_gemm<<<dim3(HDIM / 64, BROWS / BM), 512, 131072, stream>>>(A, Wt, cs, bF, bI, bC, bO, out);
}